// Round 1
// baseline (112.595 us; speedup 1.0000x reference)
//
#include <hip/hip_runtime.h>

// Problem constants
#define NB 16
#define NC 256
#define NL 1024
#define NQ 64
#define NU 64
#define N2C 512
#define NINTER 4096
#define CT 32   // gamma-channel rows per fused block
#define LT 256  // l elements per fused block

// ---------------------------------------------------------------------------
// Kernel A: A[b, c2, q] = sum_u u_i[b,u] * W[c2, u*64 + q]
// grid = 512 (c2), block = 64 (q). W read exactly once, coalesced.
// u_i addresses are wave-uniform -> scalar loads.
// ---------------------------------------------------------------------------
__global__ __launch_bounds__(64) void calc_A_kernel(
    const float* __restrict__ u_i, const float* __restrict__ W,
    float* __restrict__ A) {
  const int c2 = blockIdx.x;
  const int q = threadIdx.x;
  float acc[NB];
#pragma unroll
  for (int b = 0; b < NB; ++b) acc[b] = 0.0f;
  const float* Wrow = W + c2 * NINTER;
#pragma unroll 4
  for (int u = 0; u < NU; ++u) {
    const float w = Wrow[u * NQ + q];
#pragma unroll
    for (int b = 0; b < NB; ++b) acc[b] = fmaf(u_i[b * NU + u], w, acc[b]);
  }
#pragma unroll
  for (int b = 0; b < NB; ++b) A[(b * N2C + c2) * NQ + q] = acc[b];
}

// ---------------------------------------------------------------------------
// Kernel B: per-(b,c) mean and rstd over L=1024 (biased variance).
// grid = 4096, block = 256 (each thread owns one float4).
// ---------------------------------------------------------------------------
__global__ __launch_bounds__(256) void stats_kernel(
    const float* __restrict__ x, float* __restrict__ mean,
    float* __restrict__ rstd) {
  const int row = blockIdx.x;  // b*256 + c
  const int t = threadIdx.x;
  const float4 v = reinterpret_cast<const float4*>(x)[row * (NL / 4) + t];
  float s = v.x + v.y + v.z + v.w;
  float ss = v.x * v.x + v.y * v.y + v.z * v.z + v.w * v.w;
#pragma unroll
  for (int off = 32; off >= 1; off >>= 1) {
    s += __shfl_xor(s, off, 64);
    ss += __shfl_xor(ss, off, 64);
  }
  __shared__ float ls[4], lss[4];
  const int w = t >> 6;
  if ((t & 63) == 0) { ls[w] = s; lss[w] = ss; }
  __syncthreads();
  if (t == 0) {
    const float S = ls[0] + ls[1] + ls[2] + ls[3];
    const float SS = lss[0] + lss[1] + lss[2] + lss[3];
    const float m = S * (1.0f / NL);
    const float var = SS * (1.0f / NL) - m * m;
    mean[row] = m;
    rstd[row] = rsqrtf(var + 1e-5f);
  }
}

// ---------------------------------------------------------------------------
// Kernel C: fused style-GEMM + InstanceNorm apply + time/bias epilogue.
// grid = 16b * 8ct * 4lt = 512 blocks, block = 256 threads (4 waves).
// LDS: e tile staged in two 32KB q-halves (total static LDS ~48.5 KB ->
// 3 blocks/CU). Each thread: 8 c-rows x 4 l x {gamma,beta} accumulators.
// ---------------------------------------------------------------------------
__global__ __launch_bounds__(256) void fused_kernel(
    const float* __restrict__ x, const float* __restrict__ e,
    const float* __restrict__ tt, const float* __restrict__ V,
    const float* __restrict__ bias, const float* __restrict__ A,
    const float* __restrict__ mean, const float* __restrict__ rstd,
    float* __restrict__ out) {
  __shared__ float eT[32][LT];   // 32 KB (one q-half of the e tile)
  __shared__ float Ag[CT][NQ];   // 8 KB  (gamma rows of A)
  __shared__ float Ab[CT][NQ];   // 8 KB  (beta rows of A)
  __shared__ float sm[CT], sr[CT];

  const int blk = blockIdx.x;
  const int b = blk >> 5;         // 0..15
  const int ct = (blk >> 2) & 7;  // 0..7
  const int lt = blk & 3;         // 0..3
  const int t = threadIdx.x;

  // Stage A rows (32 gamma rows + 32 beta rows, 64 q each) into LDS.
  {
    const float4* Asg =
        reinterpret_cast<const float4*>(A + (b * N2C + ct * CT) * NQ);
    const float4* Asb =
        reinterpret_cast<const float4*>(A + (b * N2C + NC + ct * CT) * NQ);
    float4* Agv = reinterpret_cast<float4*>(&Ag[0][0]);
    float4* Abv = reinterpret_cast<float4*>(&Ab[0][0]);
#pragma unroll
    for (int k = 0; k < 2; ++k) {  // 512 float4 per array / 256 threads
      Agv[t + k * 256] = Asg[t + k * 256];
      Abv[t + k * 256] = Asb[t + k * 256];
    }
  }
  if (t < CT) {
    sm[t] = mean[b * NC + ct * CT + t];
    sr[t] = rstd[b * NC + ct * CT + t];
  }

  const int w = t >> 6, ln = t & 63;
  float4 g4[8], p4[8];
#pragma unroll
  for (int s = 0; s < 8; ++s) {
    g4[s] = make_float4(0.f, 0.f, 0.f, 0.f);
    p4[s] = make_float4(0.f, 0.f, 0.f, 0.f);
  }

  for (int half = 0; half < 2; ++half) {
    if (half) __syncthreads();  // previous compute done before overwrite
    {
      // load e[b, half*32 .. half*32+31, lt*256 .. +255] -> eT
      const float* ebase = e + b * NQ * NL + half * 32 * NL + lt * LT;
#pragma unroll
      for (int k = 0; k < 8; ++k) {
        const int idx = t + k * 256;  // 0..2047 float4 slots
        const int q = idx >> 6;       // 0..31
        const int j = idx & 63;       // float4 column
        reinterpret_cast<float4*>(&eT[q][0])[j] =
            reinterpret_cast<const float4*>(ebase + q * NL)[j];
      }
    }
    __syncthreads();

#pragma unroll 2
    for (int q0 = 0; q0 < 32; q0 += 4) {
      const float4 e0 = reinterpret_cast<const float4*>(&eT[q0 + 0][0])[ln];
      const float4 e1 = reinterpret_cast<const float4*>(&eT[q0 + 1][0])[ln];
      const float4 e2 = reinterpret_cast<const float4*>(&eT[q0 + 2][0])[ln];
      const float4 e3 = reinterpret_cast<const float4*>(&eT[q0 + 3][0])[ln];
      const int qa = half * 32 + q0;
#pragma unroll
      for (int s = 0; s < 8; ++s) {
        const int r = w * 8 + s;
        const float4 a = *reinterpret_cast<const float4*>(&Ag[r][qa]);
        g4[s].x = fmaf(a.x, e0.x, fmaf(a.y, e1.x, fmaf(a.z, e2.x, fmaf(a.w, e3.x, g4[s].x))));
        g4[s].y = fmaf(a.x, e0.y, fmaf(a.y, e1.y, fmaf(a.z, e2.y, fmaf(a.w, e3.y, g4[s].y))));
        g4[s].z = fmaf(a.x, e0.z, fmaf(a.y, e1.z, fmaf(a.z, e2.z, fmaf(a.w, e3.z, g4[s].z))));
        g4[s].w = fmaf(a.x, e0.w, fmaf(a.y, e1.w, fmaf(a.z, e2.w, fmaf(a.w, e3.w, g4[s].w))));
        const float4 c = *reinterpret_cast<const float4*>(&Ab[r][qa]);
        p4[s].x = fmaf(c.x, e0.x, fmaf(c.y, e1.x, fmaf(c.z, e2.x, fmaf(c.w, e3.x, p4[s].x))));
        p4[s].y = fmaf(c.x, e0.y, fmaf(c.y, e1.y, fmaf(c.z, e2.y, fmaf(c.w, e3.y, p4[s].y))));
        p4[s].z = fmaf(c.x, e0.z, fmaf(c.y, e1.z, fmaf(c.z, e2.z, fmaf(c.w, e3.z, p4[s].z))));
        p4[s].w = fmaf(c.x, e0.w, fmaf(c.y, e1.w, fmaf(c.z, e2.w, fmaf(c.w, e3.w, p4[s].w))));
      }
    }
  }

  // Epilogue: out = (1 + style_g + t*Vg + bias_g) * nx + style_b + t*Vb + bias_b
  const float4 tv = reinterpret_cast<const float4*>(tt + b * NL + lt * LT)[ln];
#pragma unroll
  for (int s = 0; s < 8; ++s) {
    const int r = w * 8 + s;
    const int c = ct * CT + r;
    const float vg = V[c], vb = V[c + NC];
    const float bg = bias[c], bb = bias[c + NC];
    const float m = sm[r], rs = sr[r];
    const float4 xv =
        reinterpret_cast<const float4*>(x + (b * NC + c) * NL + lt * LT)[ln];
    float4 o;
    {
      const float gx = 1.0f + g4[s].x + fmaf(tv.x, vg, bg);
      const float gy = 1.0f + g4[s].y + fmaf(tv.y, vg, bg);
      const float gz = 1.0f + g4[s].z + fmaf(tv.z, vg, bg);
      const float gw = 1.0f + g4[s].w + fmaf(tv.w, vg, bg);
      o.x = fmaf(gx, (xv.x - m) * rs, p4[s].x + fmaf(tv.x, vb, bb));
      o.y = fmaf(gy, (xv.y - m) * rs, p4[s].y + fmaf(tv.y, vb, bb));
      o.z = fmaf(gz, (xv.z - m) * rs, p4[s].z + fmaf(tv.z, vb, bb));
      o.w = fmaf(gw, (xv.w - m) * rs, p4[s].w + fmaf(tv.w, vb, bb));
    }
    reinterpret_cast<float4*>(out + (b * NC + c) * NL + lt * LT)[ln] = o;
  }
}

// ---------------------------------------------------------------------------
extern "C" void kernel_launch(void* const* d_in, const int* in_sizes, int n_in,
                              void* d_out, int out_size, void* d_ws,
                              size_t ws_size, hipStream_t stream) {
  const float* x = (const float*)d_in[0];     // (16,256,1024)
  const float* u_i = (const float*)d_in[1];   // (16,64)
  const float* e = (const float*)d_in[2];     // (16,64,1024)
  const float* tt = (const float*)d_in[3];    // (16,1,1024)
  const float* W = (const float*)d_in[4];     // (512,4096)
  const float* V = (const float*)d_in[5];     // (512,1)
  const float* bias = (const float*)d_in[6];  // (512,)
  float* out = (float*)d_out;                 // (16,256,1024)

  float* A = (float*)d_ws;                  // 16*512*64 floats = 2 MB
  float* mean = A + NB * N2C * NQ;          // 4096 floats
  float* rstd = mean + NB * NC;             // 4096 floats

  calc_A_kernel<<<N2C, 64, 0, stream>>>(u_i, W, A);
  stats_kernel<<<NB * NC, 256, 0, stream>>>(x, mean, rstd);
  fused_kernel<<<NB * 32, 256, 0, stream>>>(x, e, tt, V, bias, A, mean, rstd,
                                            out);
}

// Round 2
// 108.518 us; speedup vs baseline: 1.0376x; 1.0376x over previous
//
#include <hip/hip_runtime.h>

// Problem constants
#define NB 16
#define NC 256
#define NL 1024
#define NQ 64
#define NU 64
#define N2C 512
#define NINTER 4096
#define CT 32   // channel rows (per param) per fused block
#define LT 128  // l elements per fused block

// ---------------------------------------------------------------------------
// Kernel A v2: A[b, c2, q] = sum_u u_i[b,u] * W[c2, u*64 + q]
// grid = 512 (c2), block = 256 (4 waves; u split across waves -> 8 waves/CU,
// 4x fewer serial HBM load batches than the 1-wave version).
// ---------------------------------------------------------------------------
__global__ __launch_bounds__(256) void calc_A_kernel(
    const float* __restrict__ u_i, const float* __restrict__ W,
    float* __restrict__ A) {
  __shared__ float su[NB * NU];        // 4 KB
  __shared__ float part[4][NB][NQ];    // 16 KB
  const int t = threadIdx.x;
  const int c2 = blockIdx.x;
  const int q = t & 63;
  const int u4 = t >> 6;  // 0..3 (wave id)

  // u_i (1024 floats) -> LDS, coalesced
#pragma unroll
  for (int k = 0; k < 4; ++k) su[t + k * 256] = u_i[t + k * 256];
  __syncthreads();

  float acc[NB];
#pragma unroll
  for (int b = 0; b < NB; ++b) acc[b] = 0.0f;

  const float* Wrow = W + c2 * NINTER + u4 * 16 * NQ;
#pragma unroll
  for (int uu = 0; uu < 16; ++uu) {
    const float w = Wrow[uu * NQ + q];          // coalesced 256B/wave
    const int u = u4 * 16 + uu;                 // wave-uniform
#pragma unroll
    for (int b = 0; b < NB; ++b) acc[b] = fmaf(su[b * NU + u], w, acc[b]);
  }
#pragma unroll
  for (int b = 0; b < NB; ++b) part[u4][b][q] = acc[b];
  __syncthreads();

  // reduce 4 wave-partials; thread t handles q=t&63, b = (t>>6)*4 + i
#pragma unroll
  for (int i = 0; i < 4; ++i) {
    const int b = (t >> 6) * 4 + i;
    const float s = part[0][b][q] + part[1][b][q] + part[2][b][q] + part[3][b][q];
    A[(b * N2C + c2) * NQ + q] = s;
  }
}

// ---------------------------------------------------------------------------
// Kernel B: per-(b,c) mean and rstd over L=1024 (biased variance).
// grid = 4096, block = 256 (each thread owns one float4). BW-bound (~3 us).
// ---------------------------------------------------------------------------
__global__ __launch_bounds__(256) void stats_kernel(
    const float* __restrict__ x, float* __restrict__ mean,
    float* __restrict__ rstd) {
  const int row = blockIdx.x;  // b*256 + c
  const int t = threadIdx.x;
  const float4 v = reinterpret_cast<const float4*>(x)[row * (NL / 4) + t];
  float s = v.x + v.y + v.z + v.w;
  float ss = v.x * v.x + v.y * v.y + v.z * v.z + v.w * v.w;
#pragma unroll
  for (int off = 32; off >= 1; off >>= 1) {
    s += __shfl_xor(s, off, 64);
    ss += __shfl_xor(ss, off, 64);
  }
  __shared__ float ls[4], lss[4];
  const int w = t >> 6;
  if ((t & 63) == 0) { ls[w] = s; lss[w] = ss; }
  __syncthreads();
  if (t == 0) {
    const float S = ls[0] + ls[1] + ls[2] + ls[3];
    const float SS = lss[0] + lss[1] + lss[2] + lss[3];
    const float m = S * (1.0f / NL);
    const float var = SS * (1.0f / NL) - m * m;
    mean[row] = m;
    rstd[row] = rsqrtf(var + 1e-5f);
  }
}

// ---------------------------------------------------------------------------
// Kernel C v2: fused style-GEMM + InstanceNorm apply + time/bias epilogue.
// grid = 16b * 8ct * 8lt = 1024 blocks (4 blocks/CU), block = 256.
// e is read directly from global (4 MB total -> L1/L2-resident; LDS staging
// of cache-fit data removed). Only A goes through LDS (broadcast reads).
// Thread t: col = t&31 (float4 column of 128-l tile), rows (t>>5)*4 .. +4.
// ---------------------------------------------------------------------------
__device__ __forceinline__ void fma4(float4& acc, float a, const float4& e) {
  acc.x = fmaf(a, e.x, acc.x);
  acc.y = fmaf(a, e.y, acc.y);
  acc.z = fmaf(a, e.z, acc.z);
  acc.w = fmaf(a, e.w, acc.w);
}

__global__ __launch_bounds__(256) void fused_kernel(
    const float* __restrict__ x, const float* __restrict__ e,
    const float* __restrict__ tt, const float* __restrict__ V,
    const float* __restrict__ bias, const float* __restrict__ A,
    const float* __restrict__ mean, const float* __restrict__ rstd,
    float* __restrict__ out) {
  __shared__ float Ag[CT][NQ];  // 8 KB (gamma rows of A)
  __shared__ float Ab[CT][NQ];  // 8 KB (beta rows of A)
  __shared__ float sm[CT], sr[CT];

  const int blk = blockIdx.x;
  const int b = blk >> 6;         // 0..15
  const int ct = (blk >> 3) & 7;  // 0..7
  const int lt = blk & 7;         // 0..7
  const int t = threadIdx.x;
  const int col = t & 31;        // float4 column (l = lt*128 + col*4)
  const int rg = t >> 5;         // 0..7 row group; rows rg*4..rg*4+3

  // Stage A rows (32 gamma + 32 beta, 64 q each) into LDS.
  {
    const float4* Asg =
        reinterpret_cast<const float4*>(A + (b * N2C + ct * CT) * NQ);
    const float4* Asb =
        reinterpret_cast<const float4*>(A + (b * N2C + NC + ct * CT) * NQ);
    float4* Agv = reinterpret_cast<float4*>(&Ag[0][0]);
    float4* Abv = reinterpret_cast<float4*>(&Ab[0][0]);
#pragma unroll
    for (int k = 0; k < 2; ++k) {  // 512 float4 per array / 256 threads
      Agv[t + k * 256] = Asg[t + k * 256];
      Abv[t + k * 256] = Asb[t + k * 256];
    }
  }
  if (t < CT) {
    sm[t] = mean[b * NC + ct * CT + t];
    sr[t] = rstd[b * NC + ct * CT + t];
  }
  __syncthreads();

  float4 g[4], p[4];
#pragma unroll
  for (int i = 0; i < 4; ++i) {
    g[i] = make_float4(0.f, 0.f, 0.f, 0.f);
    p[i] = make_float4(0.f, 0.f, 0.f, 0.f);
  }

  const float* ebase = e + b * NQ * NL + lt * LT;
#pragma unroll 4
  for (int q0 = 0; q0 < NQ; q0 += 4) {
    const float4 e0 = reinterpret_cast<const float4*>(ebase + (q0 + 0) * NL)[col];
    const float4 e1 = reinterpret_cast<const float4*>(ebase + (q0 + 1) * NL)[col];
    const float4 e2 = reinterpret_cast<const float4*>(ebase + (q0 + 2) * NL)[col];
    const float4 e3 = reinterpret_cast<const float4*>(ebase + (q0 + 3) * NL)[col];
#pragma unroll
    for (int i = 0; i < 4; ++i) {
      const int r = rg * 4 + i;
      const float4 a = *reinterpret_cast<const float4*>(&Ag[r][q0]);
      fma4(g[i], a.x, e0);
      fma4(g[i], a.y, e1);
      fma4(g[i], a.z, e2);
      fma4(g[i], a.w, e3);
      const float4 c = *reinterpret_cast<const float4*>(&Ab[r][q0]);
      fma4(p[i], c.x, e0);
      fma4(p[i], c.y, e1);
      fma4(p[i], c.z, e2);
      fma4(p[i], c.w, e3);
    }
  }

  // Epilogue: out = (1 + style_g + t*Vg + bias_g) * nx + style_b + t*Vb + bias_b
  const float4 tv = reinterpret_cast<const float4*>(tt + b * NL + lt * LT)[col];
#pragma unroll
  for (int i = 0; i < 4; ++i) {
    const int r = rg * 4 + i;
    const int c = ct * CT + r;
    const float vg = V[c], vb = V[c + NC];
    const float bg = bias[c], bb = bias[c + NC];
    const float m = sm[r], rs = sr[r];
    const float4 xv =
        reinterpret_cast<const float4*>(x + (b * NC + c) * NL + lt * LT)[col];
    float4 o;
    const float gx = 1.0f + g[i].x + fmaf(tv.x, vg, bg);
    const float gy = 1.0f + g[i].y + fmaf(tv.y, vg, bg);
    const float gz = 1.0f + g[i].z + fmaf(tv.z, vg, bg);
    const float gw = 1.0f + g[i].w + fmaf(tv.w, vg, bg);
    o.x = fmaf(gx, (xv.x - m) * rs, p[i].x + fmaf(tv.x, vb, bb));
    o.y = fmaf(gy, (xv.y - m) * rs, p[i].y + fmaf(tv.y, vb, bb));
    o.z = fmaf(gz, (xv.z - m) * rs, p[i].z + fmaf(tv.z, vb, bb));
    o.w = fmaf(gw, (xv.w - m) * rs, p[i].w + fmaf(tv.w, vb, bb));
    reinterpret_cast<float4*>(out + (b * NC + c) * NL + lt * LT)[col] = o;
  }
}

// ---------------------------------------------------------------------------
extern "C" void kernel_launch(void* const* d_in, const int* in_sizes, int n_in,
                              void* d_out, int out_size, void* d_ws,
                              size_t ws_size, hipStream_t stream) {
  const float* x = (const float*)d_in[0];     // (16,256,1024)
  const float* u_i = (const float*)d_in[1];   // (16,64)
  const float* e = (const float*)d_in[2];     // (16,64,1024)
  const float* tt = (const float*)d_in[3];    // (16,1,1024)
  const float* W = (const float*)d_in[4];     // (512,4096)
  const float* V = (const float*)d_in[5];     // (512,1)
  const float* bias = (const float*)d_in[6];  // (512,)
  float* out = (float*)d_out;                 // (16,256,1024)

  float* A = (float*)d_ws;                  // 16*512*64 floats = 2 MB
  float* mean = A + NB * N2C * NQ;          // 4096 floats
  float* rstd = mean + NB * NC;             // 4096 floats

  calc_A_kernel<<<N2C, 256, 0, stream>>>(u_i, W, A);
  stats_kernel<<<NB * NC, 256, 0, stream>>>(x, mean, rstd);
  fused_kernel<<<NB * 64, 256, 0, stream>>>(x, e, tt, V, bias, A, mean, rstd,
                                            out);
}

// Round 3
// 103.195 us; speedup vs baseline: 1.0911x; 1.0516x over previous
//
#include <hip/hip_runtime.h>

// Problem constants
#define NB 16
#define NC 256
#define NL 1024
#define NQ 64
#define NU 64
#define N2C 512
#define NINTER 4096
#define CB 8  // gamma channels per fused block

// ---------------------------------------------------------------------------
// Kernel A: A[b, c2, q] = sum_u u_i[b,u] * W[c2, u*64 + q]
// grid = 512 (c2), block = 256 (4 waves; u split across waves).
// ---------------------------------------------------------------------------
__global__ __launch_bounds__(256) void calc_A_kernel(
    const float* __restrict__ u_i, const float* __restrict__ W,
    float* __restrict__ A) {
  __shared__ float su[NB * NU];      // 4 KB
  __shared__ float part[4][NB][NQ];  // 16 KB
  const int t = threadIdx.x;
  const int c2 = blockIdx.x;
  const int q = t & 63;
  const int u4 = t >> 6;  // wave id 0..3

#pragma unroll
  for (int k = 0; k < 4; ++k) su[t + k * 256] = u_i[t + k * 256];
  __syncthreads();

  float acc[NB];
#pragma unroll
  for (int b = 0; b < NB; ++b) acc[b] = 0.0f;

  const float* Wrow = W + c2 * NINTER + u4 * 16 * NQ;
#pragma unroll
  for (int uu = 0; uu < 16; ++uu) {
    const float w = Wrow[uu * NQ + q];  // coalesced 256B/wave
    const int u = u4 * 16 + uu;         // wave-uniform
#pragma unroll
    for (int b = 0; b < NB; ++b) acc[b] = fmaf(su[b * NU + u], w, acc[b]);
  }
#pragma unroll
  for (int b = 0; b < NB; ++b) part[u4][b][q] = acc[b];
  __syncthreads();

#pragma unroll
  for (int i = 0; i < 4; ++i) {
    const int b = (t >> 6) * 4 + i;
    const float s =
        part[0][b][q] + part[1][b][q] + part[2][b][q] + part[3][b][q];
    A[(b * N2C + c2) * NQ + q] = s;
  }
}

// ---------------------------------------------------------------------------
// Fused v3: stats + style-GEMM + apply, one kernel.
// grid = 16b * 32cb = 512 blocks (2 blocks/CU), block = 256 (4 waves).
// Block handles 8 gamma channels (c0..c0+7) and their 8 beta partners over
// the FULL L=1024. x read ONCE (staged to LDS, reused by apply). Thread t
// owns float4 L-column t for all 16 c2-rows -> zero e-read redundancy:
// per q, a wave reads 1KB contiguous e, each element used by one thread.
// LDS: xs 32KB + As 4KB -> 36.3KB, 2 blocks/CU fits easily.
// ---------------------------------------------------------------------------
__device__ __forceinline__ void fma4(float4& acc, float a, const float4& e) {
  acc.x = fmaf(a, e.x, acc.x);
  acc.y = fmaf(a, e.y, acc.y);
  acc.z = fmaf(a, e.z, acc.z);
  acc.w = fmaf(a, e.w, acc.w);
}

__global__ __launch_bounds__(256) void fused_kernel(
    const float* __restrict__ x, const float* __restrict__ e,
    const float* __restrict__ tt, const float* __restrict__ V,
    const float* __restrict__ bias, const float* __restrict__ A,
    float* __restrict__ out) {
  __shared__ float xs[CB][NL];       // 32 KB
  __shared__ float As[2 * CB][NQ];   // 4 KB
  __shared__ float sm[CB], sr[CB];

  const int blk = blockIdx.x;
  const int b = blk >> 5;
  const int c0 = (blk & 31) * CB;
  const int t = threadIdx.x;

  // ---- Phase 1: stage A (16 rows x 64 q) ----
  {
    const int fr = t >> 4;   // 0..15 row
    const int fc = t & 15;   // float4 col
    const int ar = (fr < CB) ? (c0 + fr) : (NC + c0 + fr - CB);
    *reinterpret_cast<float4*>(&As[fr][fc * 4]) =
        reinterpret_cast<const float4*>(A + (b * N2C + ar) * NQ)[fc];
  }

  // ---- Phase 2: x -> LDS + stats (row per 32-lane group) ----
  {
    const int rw = t >> 5;  // 0..7
    const int cl = t & 31;
    const float* xrow = x + (b * NC + c0 + rw) * NL;
    float s = 0.0f, ss = 0.0f;
#pragma unroll
    for (int k = 0; k < 8; ++k) {
      const float4 v = reinterpret_cast<const float4*>(xrow)[cl + 32 * k];
      *reinterpret_cast<float4*>(&xs[rw][(cl + 32 * k) * 4]) = v;
      s += (v.x + v.y) + (v.z + v.w);
      ss = fmaf(v.x, v.x, fmaf(v.y, v.y, fmaf(v.z, v.z, fmaf(v.w, v.w, ss))));
    }
#pragma unroll
    for (int off = 16; off >= 1; off >>= 1) {  // stays within 32-lane group
      s += __shfl_xor(s, off, 64);
      ss += __shfl_xor(ss, off, 64);
    }
    if (cl == 0) {
      const float m = s * (1.0f / NL);
      sm[rw] = m;
      sr[rw] = rsqrtf(ss * (1.0f / NL) - m * m + 1e-5f);
    }
  }
  __syncthreads();

  // ---- Phase 3: style GEMM. acc[r] = sum_q As[r][q] * e[b,q, 4t..4t+3] ----
  float4 acc[2 * CB];
#pragma unroll
  for (int r = 0; r < 2 * CB; ++r) acc[r] = make_float4(0.f, 0.f, 0.f, 0.f);

  const float* eb = e + b * NQ * NL;
#pragma unroll 1
  for (int q0 = 0; q0 < NQ; q0 += 4) {
    const float4 e0 = reinterpret_cast<const float4*>(eb + (q0 + 0) * NL)[t];
    const float4 e1 = reinterpret_cast<const float4*>(eb + (q0 + 1) * NL)[t];
    const float4 e2 = reinterpret_cast<const float4*>(eb + (q0 + 2) * NL)[t];
    const float4 e3 = reinterpret_cast<const float4*>(eb + (q0 + 3) * NL)[t];
#pragma unroll
    for (int r = 0; r < 2 * CB; ++r) {
      const float4 a = *reinterpret_cast<const float4*>(&As[r][q0]);
      fma4(acc[r], a.x, e0);
      fma4(acc[r], a.y, e1);
      fma4(acc[r], a.z, e2);
      fma4(acc[r], a.w, e3);
    }
  }

  // ---- Phase 4: apply ----
  const float4 tv = reinterpret_cast<const float4*>(tt + b * NL)[t];
#pragma unroll
  for (int r = 0; r < CB; ++r) {
    const int c = c0 + r;
    const float vg = V[c], vb = V[c + NC];
    const float bg = bias[c], bb = bias[c + NC];
    const float m = sm[r], rs = sr[r];
    const float4 xv = *reinterpret_cast<const float4*>(&xs[r][t * 4]);
    const float4 g = acc[r];
    const float4 p = acc[r + CB];
    float4 o;
    o.x = fmaf(1.0f + g.x + fmaf(tv.x, vg, bg), (xv.x - m) * rs,
               p.x + fmaf(tv.x, vb, bb));
    o.y = fmaf(1.0f + g.y + fmaf(tv.y, vg, bg), (xv.y - m) * rs,
               p.y + fmaf(tv.y, vb, bb));
    o.z = fmaf(1.0f + g.z + fmaf(tv.z, vg, bg), (xv.z - m) * rs,
               p.z + fmaf(tv.z, vb, bb));
    o.w = fmaf(1.0f + g.w + fmaf(tv.w, vg, bg), (xv.w - m) * rs,
               p.w + fmaf(tv.w, vb, bb));
    reinterpret_cast<float4*>(out + (b * NC + c) * NL)[t] = o;
  }
}

// ---------------------------------------------------------------------------
extern "C" void kernel_launch(void* const* d_in, const int* in_sizes, int n_in,
                              void* d_out, int out_size, void* d_ws,
                              size_t ws_size, hipStream_t stream) {
  const float* x = (const float*)d_in[0];     // (16,256,1024)
  const float* u_i = (const float*)d_in[1];   // (16,64)
  const float* e = (const float*)d_in[2];     // (16,64,1024)
  const float* tt = (const float*)d_in[3];    // (16,1,1024)
  const float* W = (const float*)d_in[4];     // (512,4096)
  const float* V = (const float*)d_in[5];     // (512,1)
  const float* bias = (const float*)d_in[6];  // (512,)
  float* out = (float*)d_out;                 // (16,256,1024)

  float* A = (float*)d_ws;  // 16*512*64 floats = 2 MB

  calc_A_kernel<<<N2C, 256, 0, stream>>>(u_i, W, A);
  fused_kernel<<<NB * 32, 256, 0, stream>>>(x, e, tt, V, bias, A, out);
}

// Round 4
// 102.602 us; speedup vs baseline: 1.0974x; 1.0058x over previous
//
#include <hip/hip_runtime.h>

// Problem constants
#define NB 16
#define NC 256
#define NL 1024
#define NQ 64
#define NU 64
#define N2C 512
#define NINTER 4096
#define CB 8  // gamma channels per fused block

// ---------------------------------------------------------------------------
// Kernel A: A[b, c2, q] = sum_u u_i[b,u] * W[c2, u*64 + q]
// grid = 512 (c2), block = 256 (4 waves; u split across waves).
// Memory-latency bound, ~2-3 us; W read exactly once, coalesced.
// ---------------------------------------------------------------------------
__global__ __launch_bounds__(256) void calc_A_kernel(
    const float* __restrict__ u_i, const float* __restrict__ W,
    float* __restrict__ A) {
  __shared__ float su[NB * NU];      // 4 KB
  __shared__ float part[4][NB][NQ];  // 16 KB
  const int t = threadIdx.x;
  const int c2 = blockIdx.x;
  const int q = t & 63;
  const int u4 = t >> 6;  // wave id 0..3

#pragma unroll
  for (int k = 0; k < 4; ++k) su[t + k * 256] = u_i[t + k * 256];
  __syncthreads();

  float acc[NB];
#pragma unroll
  for (int b = 0; b < NB; ++b) acc[b] = 0.0f;

  const float* Wrow = W + c2 * NINTER + u4 * 16 * NQ;
#pragma unroll
  for (int uu = 0; uu < 16; ++uu) {
    const float w = Wrow[uu * NQ + q];  // coalesced 256B/wave
    const int u = u4 * 16 + uu;         // wave-uniform
#pragma unroll
    for (int b = 0; b < NB; ++b) acc[b] = fmaf(su[b * NU + u], w, acc[b]);
  }
#pragma unroll
  for (int b = 0; b < NB; ++b) part[u4][b][q] = acc[b];
  __syncthreads();

#pragma unroll
  for (int i = 0; i < 4; ++i) {
    const int b = (t >> 6) * 4 + i;
    const float s =
        part[0][b][q] + part[1][b][q] + part[2][b][q] + part[3][b][q];
    A[(b * N2C + c2) * NQ + q] = s;
  }
}

// ---------------------------------------------------------------------------
// Fused v4: stats + style-GEMM + apply, one kernel.
// grid = 16b * 32cb = 512 blocks (2 blocks/CU), block = 256 (4 waves).
// v4 change vs v3: the e-loads of the GEMM loop are register double-buffered
// (prefetch next 4 rows while FMA-ing current 4; first prefetch issued before
// the x/stats phase) -> the per-step `s_waitcnt vmcnt(0)` stall that
// `#pragma unroll 1` forced in v3 is hidden under FMA / phase-2 work.
// ---------------------------------------------------------------------------
__device__ __forceinline__ void fma4(float4& acc, float a, const float4& e) {
  acc.x = fmaf(a, e.x, acc.x);
  acc.y = fmaf(a, e.y, acc.y);
  acc.z = fmaf(a, e.z, acc.z);
  acc.w = fmaf(a, e.w, acc.w);
}

__global__ __launch_bounds__(256) void fused_kernel(
    const float* __restrict__ x, const float* __restrict__ e,
    const float* __restrict__ tt, const float* __restrict__ V,
    const float* __restrict__ bias, const float* __restrict__ A,
    float* __restrict__ out) {
  __shared__ float xs[CB][NL];      // 32 KB
  __shared__ float As[2 * CB][NQ];  // 4 KB
  __shared__ float sm[CB], sr[CB];

  const int blk = blockIdx.x;
  const int b = blk >> 5;
  const int c0 = (blk & 31) * CB;
  const int t = threadIdx.x;

  // ---- Issue first e prefetch + tt load immediately (latency hides under
  //      phases 1-2). Thread t owns float4 L-column t; e row stride = 256 f4.
  const float4* ef = reinterpret_cast<const float4*>(e + b * NQ * NL) + t;
  float4 n0 = ef[0 * 256];
  float4 n1 = ef[1 * 256];
  float4 n2 = ef[2 * 256];
  float4 n3 = ef[3 * 256];
  const float4 tv = reinterpret_cast<const float4*>(tt + b * NL)[t];

  // ---- Phase 1: stage A (16 rows x 64 q) into LDS ----
  {
    const int fr = t >> 4;  // 0..15 row
    const int fc = t & 15;  // float4 col
    const int ar = (fr < CB) ? (c0 + fr) : (NC + c0 + fr - CB);
    *reinterpret_cast<float4*>(&As[fr][fc * 4]) =
        reinterpret_cast<const float4*>(A + (b * N2C + ar) * NQ)[fc];
  }

  // ---- Phase 2: x -> LDS + stats (row per 32-lane group) ----
  {
    const int rw = t >> 5;  // 0..7
    const int cl = t & 31;
    const float* xrow = x + (b * NC + c0 + rw) * NL;
    float s = 0.0f, ss = 0.0f;
#pragma unroll
    for (int k = 0; k < 8; ++k) {
      const float4 v = reinterpret_cast<const float4*>(xrow)[cl + 32 * k];
      *reinterpret_cast<float4*>(&xs[rw][(cl + 32 * k) * 4]) = v;
      s += (v.x + v.y) + (v.z + v.w);
      ss = fmaf(v.x, v.x, fmaf(v.y, v.y, fmaf(v.z, v.z, fmaf(v.w, v.w, ss))));
    }
#pragma unroll
    for (int off = 16; off >= 1; off >>= 1) {  // stays within 32-lane group
      s += __shfl_xor(s, off, 64);
      ss += __shfl_xor(ss, off, 64);
    }
    if (cl == 0) {
      const float m = s * (1.0f / NL);
      sm[rw] = m;
      sr[rw] = rsqrtf(ss * (1.0f / NL) - m * m + 1e-5f);
    }
  }
  __syncthreads();

  // ---- Phase 3: style GEMM, register-double-buffered e ----
  float4 acc[2 * CB];
#pragma unroll
  for (int r = 0; r < 2 * CB; ++r) acc[r] = make_float4(0.f, 0.f, 0.f, 0.f);

#pragma unroll 1
  for (int q0 = 0; q0 < NQ; q0 += 4) {
    const float4 e0 = n0, e1 = n1, e2 = n2, e3 = n3;
    if (q0 + 4 < NQ) {
      const float4* nf = ef + (q0 + 4) * 256;
      n0 = nf[0 * 256];
      n1 = nf[1 * 256];
      n2 = nf[2 * 256];
      n3 = nf[3 * 256];
    }
#pragma unroll
    for (int r = 0; r < 2 * CB; ++r) {
      const float4 a = *reinterpret_cast<const float4*>(&As[r][q0]);
      fma4(acc[r], a.x, e0);
      fma4(acc[r], a.y, e1);
      fma4(acc[r], a.z, e2);
      fma4(acc[r], a.w, e3);
    }
  }

  // ---- Phase 4: apply ----
#pragma unroll
  for (int r = 0; r < CB; ++r) {
    const int c = c0 + r;
    const float vg = V[c], vb = V[c + NC];
    const float bg = bias[c], bb = bias[c + NC];
    const float m = sm[r], rs = sr[r];
    const float4 xv = *reinterpret_cast<const float4*>(&xs[r][t * 4]);
    const float4 g = acc[r];
    const float4 p = acc[r + CB];
    float4 o;
    o.x = fmaf(1.0f + g.x + fmaf(tv.x, vg, bg), (xv.x - m) * rs,
               p.x + fmaf(tv.x, vb, bb));
    o.y = fmaf(1.0f + g.y + fmaf(tv.y, vg, bg), (xv.y - m) * rs,
               p.y + fmaf(tv.y, vb, bb));
    o.z = fmaf(1.0f + g.z + fmaf(tv.z, vg, bg), (xv.z - m) * rs,
               p.z + fmaf(tv.z, vb, bb));
    o.w = fmaf(1.0f + g.w + fmaf(tv.w, vg, bg), (xv.w - m) * rs,
               p.w + fmaf(tv.w, vb, bb));
    reinterpret_cast<float4*>(out + (b * NC + c) * NL)[t] = o;
  }
}

// ---------------------------------------------------------------------------
extern "C" void kernel_launch(void* const* d_in, const int* in_sizes, int n_in,
                              void* d_out, int out_size, void* d_ws,
                              size_t ws_size, hipStream_t stream) {
  const float* x = (const float*)d_in[0];     // (16,256,1024)
  const float* u_i = (const float*)d_in[1];   // (16,64)
  const float* e = (const float*)d_in[2];     // (16,64,1024)
  const float* tt = (const float*)d_in[3];    // (16,1,1024)
  const float* W = (const float*)d_in[4];     // (512,4096)
  const float* V = (const float*)d_in[5];     // (512,1)
  const float* bias = (const float*)d_in[6];  // (512,)
  float* out = (float*)d_out;                 // (16,256,1024)

  float* A = (float*)d_ws;  // 16*512*64 floats = 2 MB

  calc_A_kernel<<<N2C, 256, 0, stream>>>(u_i, W, A);
  fused_kernel<<<NB * 32, 256, 0, stream>>>(x, e, tt, V, bias, A, out);
}